// Round 7
// baseline (167.775 us; speedup 1.0000x reference)
//
#include <hip/hip_runtime.h>
#include <stdint.h>

#define BATCH  4
#define CCH    128
#define GRID_H 128
#define GRID_W 128
#define NNODE  (GRID_H*GRID_W)   // 16384
#define NHEAD  8
#define DH     16
#define WPAD   68                // padded k2 row (64 + 4), keeps b128 align
#define WROWS  144               // 128 ch + 8 aS + 8 aD

typedef __attribute__((ext_vector_type(8))) short short8;
typedef __attribute__((ext_vector_type(4))) float f32x4;
typedef __attribute__((ext_vector_type(4))) unsigned u32x4;

__device__ inline unsigned short f2bf(float f){
    unsigned u = __float_as_uint(f);
    return (unsigned short)((u + 0x7FFFu + ((u >> 16) & 1u)) >> 16);
}
__device__ inline unsigned packbf(float a, float b){
    return (unsigned)f2bf(a) | ((unsigned)f2bf(b) << 16);
}
__device__ inline float bflo(unsigned u){ return __uint_as_float(u << 16); }
__device__ inline float bfhi(unsigned u){ return __uint_as_float(u & 0xFFFF0000u); }

// ---------------------------------------------------------------------------
// kW: pack augmented W' (144 cols: W | W@attS_h | W@attD_h) to bf16 k-pairs,
// co-major: Wb[co*WPAD + k2] = {bf16 W'[2k2][co], bf16 W'[2k2+1][co]}.
// ---------------------------------------------------------------------------
__global__ void kW(const float* __restrict__ Wl, const float* __restrict__ attS,
                   const float* __restrict__ attD, unsigned* __restrict__ Wb)
{
    __shared__ float Wa[8][16];
    const int t = threadIdx.x;
    const int cbase = blockIdx.x * 8;
    if (t < 128){
        int cl = t >> 4, j = t & 15;
        const float* av = (j < 8 ? attS + j*DH : attD + (j-8)*DH);
        const float* wr = Wl + (size_t)(cbase + cl)*CCH + (j & 7)*DH;
        float s = 0.f;
        #pragma unroll
        for (int d = 0; d < DH; ++d) s += wr[d]*av[d];
        Wa[cl][j] = s;
    }
    __syncthreads();
    for (int it = 0; it < 3; ++it){
        int flat = it*256 + t;
        if (flat < 576){
            int k2l = flat / 144, co = flat % 144;
            int k2 = blockIdx.x*4 + k2l;
            float w0, w1;
            if (co < CCH){
                w0 = Wl[(size_t)(2*k2)*CCH + co];
                w1 = Wl[(size_t)(2*k2+1)*CCH + co];
            } else {
                w0 = Wa[2*k2l][co-CCH];
                w1 = Wa[2*k2l+1][co-CCH];
            }
            Wb[co*WPAD + k2] = packbf(w0, w1);
        }
    }
}

// ---------------------------------------------------------------------------
// kA: D[m=co][n=node] = W'^T x (A=W', B=x). C/D layout gives each lane 4
// CONSECUTIVE channels -> epilogue is coalesced b64 bf16 stores in standard
// [n][ch] order. x fragments built direct from global, double-buffered.
// ---------------------------------------------------------------------------
__global__ __launch_bounds__(256, 3) void kA(
    const float* __restrict__ x, const unsigned* __restrict__ Wbg,
    unsigned short* __restrict__ xpb, float* __restrict__ scb)
{
    __shared__ __align__(16) unsigned WbL[WROWS*WPAD];   // 39168 B

    const int t  = threadIdx.x;
    const int b  = blockIdx.y;
    const int n0 = blockIdx.x * 128;

    #pragma unroll
    for (int it = 0; it < 10; ++it){
        int f4 = it*256 + t;
        if (f4 < (WROWS*WPAD)/4)
            *(u32x4*)(&WbL[f4*4]) = *(const u32x4*)(Wbg + (size_t)f4*4);
    }
    __syncthreads();

    const int w = t >> 6, lane = t & 63;
    const int col = lane & 15, q = lane >> 4;
    const float* xb = x + (size_t)b*CCH*NNODE;
    const int nA = n0 + 2*w*16 + col;      // node-tile 0 node of this lane
    const int nB = nA + 16;                // node-tile 1

    f32x4 acc[2][9];
    #pragma unroll
    for (int mi = 0; mi < 2; ++mi)
        #pragma unroll
        for (int ct = 0; ct < 9; ++ct) acc[mi][ct] = (f32x4)(0.f);

    float xrA[8], xrB[8], x2A[8], x2B[8];
    #pragma unroll
    for (int j = 0; j < 8; ++j){
        const size_t co = (size_t)(q*8 + j)*NNODE;
        xrA[j] = xb[co + nA];
        xrB[j] = xb[co + nB];
    }

    union U { u32x4 u; short8 s; };
    #pragma unroll
    for (int kc = 0; kc < 4; ++kc){
        if (kc < 3){
            #pragma unroll
            for (int j = 0; j < 8; ++j){
                const size_t co = (size_t)((kc+1)*32 + q*8 + j)*NNODE;
                x2A[j] = xb[co + nA];
                x2B[j] = xb[co + nB];
            }
        }
        U fb0, fb1;
        #pragma unroll
        for (int i = 0; i < 4; ++i){
            fb0.u[i] = packbf(xrA[2*i], xrA[2*i+1]);
            fb1.u[i] = packbf(xrB[2*i], xrB[2*i+1]);
        }
        const int kof = kc*16 + q*4;
        #pragma unroll
        for (int ct = 0; ct < 9; ++ct){
            U fa; fa.u = *(const u32x4*)(&WbL[(ct*16+col)*WPAD + kof]);
            acc[0][ct] = __builtin_amdgcn_mfma_f32_16x16x32_bf16(fa.s, fb0.s, acc[0][ct], 0, 0, 0);
            acc[1][ct] = __builtin_amdgcn_mfma_f32_16x16x32_bf16(fa.s, fb1.s, acc[1][ct], 0, 0, 0);
        }
        #pragma unroll
        for (int j = 0; j < 8; ++j){ xrA[j] = x2A[j]; xrB[j] = x2B[j]; }
    }

    // epilogue: lane holds co = ct*16 + q*4 + r for node (col). Standard layout.
    unsigned short* xr = xpb + (size_t)b*NNODE*CCH;
    float*          sr = scb + (size_t)b*NNODE*16;
    #pragma unroll
    for (int mi = 0; mi < 2; ++mi){
        const int n = mi ? nB : nA;
        #pragma unroll
        for (int ct = 0; ct < 8; ++ct){
            uint2 p;
            p.x = packbf(acc[mi][ct][0], acc[mi][ct][1]);
            p.y = packbf(acc[mi][ct][2], acc[mi][ct][3]);
            *(uint2*)(xr + (size_t)n*CCH + ct*16 + q*4) = p;
        }
        #pragma unroll
        for (int r = 0; r < 4; ++r)
            sr[(size_t)n*16 + q*4 + r] = acc[mi][8][r];   // 0..7 aS, 8..15 aD
    }
}

// ---------------------------------------------------------------------------
// kB: 32 nodes/block; half-wave per node, 4 channels/lane, 2-deep software
// pipeline; (256,8) -> 8 blocks/CU (2048 thr) to hide L2 gather latency.
// ---------------------------------------------------------------------------
__device__ inline void kb_issue(int n, const float* __restrict__ scB,
                                const uint2* __restrict__ xvb, int h, int l2,
                                int* vm, float* ad, float sc[9], uint2 xv[9])
{
    const int rr = n >> 7, cc = n & 127;
    const bool vU = rr > 0, vD = rr < GRID_H-1, vL = cc > 0, vR = cc < GRID_W-1;
    int m = 0;
    #pragma unroll
    for (int e = 0; e < 9; ++e){
        const int dr = e/3 - 1, dc = e%3 - 1;
        const bool vr_ = (dr < 0) ? vU : (dr > 0 ? vD : true);
        const bool vc_ = (dc < 0) ? vL : (dc > 0 ? vR : true);
        const bool v = vr_ && vc_;
        const int src = v ? (n + dr*GRID_W + dc) : n;
        m |= ((int)v) << e;
        sc[e] = scB[(size_t)src*16 + h];
        xv[e] = xvb[(size_t)src*32 + l2];
    }
    *ad = scB[(size_t)n*16 + 8 + h];
    *vm = m;
}

__global__ __launch_bounds__(256, 8) void kB(
    const unsigned short* __restrict__ xpb, const float* __restrict__ scb,
    const float* __restrict__ bias, const float* __restrict__ gamma,
    const float* __restrict__ beta, float* __restrict__ out)
{
    __shared__ float outT[CCH][33];
    const int t = threadIdx.x, w = t >> 6, lane = t & 63;
    const int h2 = lane >> 5, l2 = lane & 31;
    const int b  = blockIdx.y;
    const int n0 = blockIdx.x * 32;
    const uint2* xvb = (const uint2*)(xpb + (size_t)b*NNODE*CCH);
    const float* scB = scb + (size_t)b*NNODE*16;
    const int h = l2 >> 2;
    const f32x4 bi = *(const f32x4*)(bias  + 4*l2);
    const f32x4 ga = *(const f32x4*)(gamma + 4*l2);
    const f32x4 be = *(const f32x4*)(beta  + 4*l2);

    float scP[2][9]; uint2 xvP[2][9]; float adP[2]; int vmP[2];

    #define NODE(i) (n0 + w*8 + 2*(i) + h2)
    kb_issue(NODE(0), scB, xvb, h, l2, &vmP[0], &adP[0], scP[0], xvP[0]);

    #pragma unroll
    for (int i = 0; i < 4; ++i){
        const int cur = i & 1;
        if (i < 3)
            kb_issue(NODE(i+1), scB, xvb, h, l2, &vmP[cur^1], &adP[cur^1], scP[cur^1], xvP[cur^1]);

        const int vm = vmP[cur];
        const float* sc = scP[cur];
        const uint2* xv = xvP[cur];
        const float ad = adP[cur];
        const int nl = w*8 + 2*i + h2;

        float wt[9], den = 0.f;
        #pragma unroll
        for (int e = 0; e < 9; ++e){
            float sv = sc[e] + ad;
            sv = fmaxf(sv, 0.2f*sv);               // leaky relu
            sv = ((vm >> e) & 1) ? sv : -1e30f;    // exp(-1e30) -> 0
            float ex = __expf(sv);
            wt[e] = ex; den += ex;
        }
        den += wt[4];                              // appended self-loop
        const float inv = __builtin_amdgcn_rcpf(den);

        float a0 = 0.f, a1 = 0.f, a2 = 0.f, a3 = 0.f;
        #pragma unroll
        for (int e = 0; e < 9; ++e){
            float f = wt[e] * inv;
            if (e == 4) f += f;                    // self counted twice
            a0 += f * bflo(xv[e].x);
            a1 += f * bfhi(xv[e].x);
            a2 += f * bflo(xv[e].y);
            a3 += f * bfhi(xv[e].y);
        }

        float o0 = a0 + bi[0], o1 = a1 + bi[1], o2 = a2 + bi[2], o3 = a3 + bi[3];
        o0 = o0 > 0.f ? o0 : __expf(o0) - 1.f;
        o1 = o1 > 0.f ? o1 : __expf(o1) - 1.f;
        o2 = o2 > 0.f ? o2 : __expf(o2) - 1.f;
        o3 = o3 > 0.f ? o3 : __expf(o3) - 1.f;

        float sm = (o0 + o1) + (o2 + o3);
        float sq = o0*o0 + o1*o1 + o2*o2 + o3*o3;
        #pragma unroll
        for (int off = 1; off <= 16; off <<= 1){
            sm += __shfl_xor(sm, off, 64);
            sq += __shfl_xor(sq, off, 64);
        }
        const float mu  = sm * (1.f/128.f);
        float var = sq * (1.f/128.f) - mu*mu;
        var = var < 0.f ? 0.f : var;
        const float rstd = __builtin_amdgcn_rsqf(var + 1e-5f);
        outT[4*l2+0][nl] = (o0 - mu)*rstd*ga[0] + be[0];
        outT[4*l2+1][nl] = (o1 - mu)*rstd*ga[1] + be[1];
        outT[4*l2+2][nl] = (o2 - mu)*rstd*ga[2] + be[2];
        outT[4*l2+3][nl] = (o3 - mu)*rstd*ga[3] + be[3];
    }
    #undef NODE
    __syncthreads();

    float* ob = out + (size_t)b*CCH*NNODE + n0;
    #pragma unroll
    for (int it = 0; it < 16; ++it){
        const int c = it*8 + (t >> 5);
        const int coln = t & 31;
        ob[(size_t)c*NNODE + coln] = outT[c][coln];
    }
}

extern "C" void kernel_launch(void* const* d_in, const int* in_sizes, int n_in,
                              void* d_out, int out_size, void* d_ws, size_t ws_size,
                              hipStream_t stream)
{
    const float* x    = (const float*)d_in[0];
    const float* Wl   = (const float*)d_in[1];
    const float* attS = (const float*)d_in[2];
    const float* attD = (const float*)d_in[3];
    const float* bias = (const float*)d_in[4];
    const float* gamma= (const float*)d_in[5];
    const float* beta = (const float*)d_in[6];
    float* out = (float*)d_out;

    unsigned short* xpb = (unsigned short*)d_ws;                    // B*N*128 bf16
    float*          scb = (float*)(xpb + (size_t)BATCH*NNODE*CCH);  // B*N*16 f32
    unsigned*       Wb  = (unsigned*)(scb + (size_t)BATCH*NNODE*16);// 144*68 u32

    kW<<<dim3(16), 256, 0, stream>>>(Wl, attS, attD, Wb);
    kA<<<dim3(NNODE/128, BATCH), 256, 0, stream>>>(x, Wb, xpb, scb);
    kB<<<dim3(NNODE/32, BATCH), 256, 0, stream>>>(xpb, scb, bias, gamma, beta, out);
}

// Round 8
// 119.324 us; speedup vs baseline: 1.4061x; 1.4061x over previous
//
#include <hip/hip_runtime.h>
#include <stdint.h>

#define BATCH  4
#define CCH    128
#define GRID_H 128
#define GRID_W 128
#define NNODE  (GRID_H*GRID_W)   // 16384
#define NHEAD  8
#define DH     16
#define WPAD   68                // padded k2 row (64 + 4), keeps b128 align
#define WROWS  144               // 128 ch + 8 aS + 8 aD

typedef __attribute__((ext_vector_type(8))) short short8;
typedef __attribute__((ext_vector_type(4))) float f32x4;
typedef __attribute__((ext_vector_type(4))) unsigned u32x4;

__device__ inline unsigned short f2bf(float f){
    unsigned u = __float_as_uint(f);
    return (unsigned short)((u + 0x7FFFu + ((u >> 16) & 1u)) >> 16);
}
__device__ inline unsigned packbf(float a, float b){
    return (unsigned)f2bf(a) | ((unsigned)f2bf(b) << 16);
}
__device__ inline float bflo(unsigned u){ return __uint_as_float(u << 16); }
__device__ inline float bfhi(unsigned u){ return __uint_as_float(u & 0xFFFF0000u); }

// ---------------------------------------------------------------------------
// kW: pack augmented W' (144 cols: W | W@attS_h | W@attD_h) to bf16 k-pairs,
// co-major: Wb[co*WPAD + k2] = {bf16 W'[2k2][co], bf16 W'[2k2+1][co]}.
// ---------------------------------------------------------------------------
__global__ void kW(const float* __restrict__ Wl, const float* __restrict__ attS,
                   const float* __restrict__ attD, unsigned* __restrict__ Wb)
{
    __shared__ float Wa[8][16];
    const int t = threadIdx.x;
    const int cbase = blockIdx.x * 8;
    if (t < 128){
        int cl = t >> 4, j = t & 15;
        const float* av = (j < 8 ? attS + j*DH : attD + (j-8)*DH);
        const float* wr = Wl + (size_t)(cbase + cl)*CCH + (j & 7)*DH;
        float s = 0.f;
        #pragma unroll
        for (int d = 0; d < DH; ++d) s += wr[d]*av[d];
        Wa[cl][j] = s;
    }
    __syncthreads();
    for (int it = 0; it < 3; ++it){
        int flat = it*256 + t;
        if (flat < 576){
            int k2l = flat / 144, co = flat % 144;
            int k2 = blockIdx.x*4 + k2l;
            float w0, w1;
            if (co < CCH){
                w0 = Wl[(size_t)(2*k2)*CCH + co];
                w1 = Wl[(size_t)(2*k2+1)*CCH + co];
            } else {
                w0 = Wa[2*k2l][co-CCH];
                w1 = Wa[2*k2l+1][co-CCH];
            }
            Wb[co*WPAD + k2] = packbf(w0, w1);
        }
    }
}

// ---------------------------------------------------------------------------
// kA: D[m=co][n=node] = W'^T x (A=W', B=x). C/D layout gives each lane 4
// CONSECUTIVE channels -> epilogue is coalesced b64 bf16 stores in standard
// [n][ch] order. x fragments built direct from global, double-buffered.
// ---------------------------------------------------------------------------
__global__ __launch_bounds__(256, 3) void kA(
    const float* __restrict__ x, const unsigned* __restrict__ Wbg,
    unsigned short* __restrict__ xpb, float* __restrict__ scb)
{
    __shared__ __align__(16) unsigned WbL[WROWS*WPAD];   // 39168 B

    const int t  = threadIdx.x;
    const int b  = blockIdx.y;
    const int n0 = blockIdx.x * 128;

    #pragma unroll
    for (int it = 0; it < 10; ++it){
        int f4 = it*256 + t;
        if (f4 < (WROWS*WPAD)/4)
            *(u32x4*)(&WbL[f4*4]) = *(const u32x4*)(Wbg + (size_t)f4*4);
    }
    __syncthreads();

    const int w = t >> 6, lane = t & 63;
    const int col = lane & 15, q = lane >> 4;
    const float* xb = x + (size_t)b*CCH*NNODE;
    const int nA = n0 + 2*w*16 + col;      // node-tile 0 node of this lane
    const int nB = nA + 16;                // node-tile 1

    f32x4 acc[2][9];
    #pragma unroll
    for (int mi = 0; mi < 2; ++mi)
        #pragma unroll
        for (int ct = 0; ct < 9; ++ct) acc[mi][ct] = (f32x4)(0.f);

    float xrA[8], xrB[8], x2A[8], x2B[8];
    #pragma unroll
    for (int j = 0; j < 8; ++j){
        const size_t co = (size_t)(q*8 + j)*NNODE;
        xrA[j] = xb[co + nA];
        xrB[j] = xb[co + nB];
    }

    union U { u32x4 u; short8 s; };
    #pragma unroll
    for (int kc = 0; kc < 4; ++kc){
        if (kc < 3){
            #pragma unroll
            for (int j = 0; j < 8; ++j){
                const size_t co = (size_t)((kc+1)*32 + q*8 + j)*NNODE;
                x2A[j] = xb[co + nA];
                x2B[j] = xb[co + nB];
            }
        }
        U fb0, fb1;
        #pragma unroll
        for (int i = 0; i < 4; ++i){
            fb0.u[i] = packbf(xrA[2*i], xrA[2*i+1]);
            fb1.u[i] = packbf(xrB[2*i], xrB[2*i+1]);
        }
        const int kof = kc*16 + q*4;
        #pragma unroll
        for (int ct = 0; ct < 9; ++ct){
            U fa; fa.u = *(const u32x4*)(&WbL[(ct*16+col)*WPAD + kof]);
            acc[0][ct] = __builtin_amdgcn_mfma_f32_16x16x32_bf16(fa.s, fb0.s, acc[0][ct], 0, 0, 0);
            acc[1][ct] = __builtin_amdgcn_mfma_f32_16x16x32_bf16(fa.s, fb1.s, acc[1][ct], 0, 0, 0);
        }
        #pragma unroll
        for (int j = 0; j < 8; ++j){ xrA[j] = x2A[j]; xrB[j] = x2B[j]; }
    }

    // epilogue: lane holds co = ct*16 + q*4 + r for node (col). Standard layout.
    unsigned short* xr = xpb + (size_t)b*NNODE*CCH;
    float*          sr = scb + (size_t)b*NNODE*16;
    #pragma unroll
    for (int mi = 0; mi < 2; ++mi){
        const int n = mi ? nB : nA;
        #pragma unroll
        for (int ct = 0; ct < 8; ++ct){
            uint2 p;
            p.x = packbf(acc[mi][ct][0], acc[mi][ct][1]);
            p.y = packbf(acc[mi][ct][2], acc[mi][ct][3]);
            *(uint2*)(xr + (size_t)n*CCH + ct*16 + q*4) = p;
        }
        #pragma unroll
        for (int r = 0; r < 4; ++r)
            sr[(size_t)n*16 + q*4 + r] = acc[mi][8][r];   // 0..7 aS, 8..15 aD
    }
}

// ---------------------------------------------------------------------------
// kB: 32 nodes/block; half-wave per node, 4 channels/lane, 2-deep software
// pipeline. (256,4): VGPR=64 (no spills) + 16.9 KB LDS -> scheduler can pack
// 8 blocks/CU for latency hiding.
// ---------------------------------------------------------------------------
__device__ inline void kb_issue(int n, const float* __restrict__ scB,
                                const uint2* __restrict__ xvb, int h, int l2,
                                int* vm, float* ad, float sc[9], uint2 xv[9])
{
    const int rr = n >> 7, cc = n & 127;
    const bool vU = rr > 0, vD = rr < GRID_H-1, vL = cc > 0, vR = cc < GRID_W-1;
    int m = 0;
    #pragma unroll
    for (int e = 0; e < 9; ++e){
        const int dr = e/3 - 1, dc = e%3 - 1;
        const bool vr_ = (dr < 0) ? vU : (dr > 0 ? vD : true);
        const bool vc_ = (dc < 0) ? vL : (dc > 0 ? vR : true);
        const bool v = vr_ && vc_;
        const int src = v ? (n + dr*GRID_W + dc) : n;
        m |= ((int)v) << e;
        sc[e] = scB[(size_t)src*16 + h];
        xv[e] = xvb[(size_t)src*32 + l2];
    }
    *ad = scB[(size_t)n*16 + 8 + h];
    *vm = m;
}

__global__ __launch_bounds__(256, 4) void kB(
    const unsigned short* __restrict__ xpb, const float* __restrict__ scb,
    const float* __restrict__ bias, const float* __restrict__ gamma,
    const float* __restrict__ beta, float* __restrict__ out)
{
    __shared__ float outT[CCH][33];
    const int t = threadIdx.x, w = t >> 6, lane = t & 63;
    const int h2 = lane >> 5, l2 = lane & 31;
    const int b  = blockIdx.y;
    const int n0 = blockIdx.x * 32;
    const uint2* xvb = (const uint2*)(xpb + (size_t)b*NNODE*CCH);
    const float* scB = scb + (size_t)b*NNODE*16;
    const int h = l2 >> 2;
    const f32x4 bi = *(const f32x4*)(bias  + 4*l2);
    const f32x4 ga = *(const f32x4*)(gamma + 4*l2);
    const f32x4 be = *(const f32x4*)(beta  + 4*l2);

    float scP[2][9]; uint2 xvP[2][9]; float adP[2]; int vmP[2];

    #define NODE(i) (n0 + w*8 + 2*(i) + h2)
    kb_issue(NODE(0), scB, xvb, h, l2, &vmP[0], &adP[0], scP[0], xvP[0]);

    #pragma unroll
    for (int i = 0; i < 4; ++i){
        const int cur = i & 1;
        if (i < 3)
            kb_issue(NODE(i+1), scB, xvb, h, l2, &vmP[cur^1], &adP[cur^1], scP[cur^1], xvP[cur^1]);

        const int vm = vmP[cur];
        const float* sc = scP[cur];
        const uint2* xv = xvP[cur];
        const float ad = adP[cur];
        const int nl = w*8 + 2*i + h2;

        float wt[9], den = 0.f;
        #pragma unroll
        for (int e = 0; e < 9; ++e){
            float sv = sc[e] + ad;
            sv = fmaxf(sv, 0.2f*sv);               // leaky relu
            sv = ((vm >> e) & 1) ? sv : -1e30f;    // exp(-1e30) -> 0
            float ex = __expf(sv);
            wt[e] = ex; den += ex;
        }
        den += wt[4];                              // appended self-loop
        const float inv = __builtin_amdgcn_rcpf(den);

        float a0 = 0.f, a1 = 0.f, a2 = 0.f, a3 = 0.f;
        #pragma unroll
        for (int e = 0; e < 9; ++e){
            float f = wt[e] * inv;
            if (e == 4) f += f;                    // self counted twice
            a0 += f * bflo(xv[e].x);
            a1 += f * bfhi(xv[e].x);
            a2 += f * bflo(xv[e].y);
            a3 += f * bfhi(xv[e].y);
        }

        float o0 = a0 + bi[0], o1 = a1 + bi[1], o2 = a2 + bi[2], o3 = a3 + bi[3];
        o0 = o0 > 0.f ? o0 : __expf(o0) - 1.f;
        o1 = o1 > 0.f ? o1 : __expf(o1) - 1.f;
        o2 = o2 > 0.f ? o2 : __expf(o2) - 1.f;
        o3 = o3 > 0.f ? o3 : __expf(o3) - 1.f;

        float sm = (o0 + o1) + (o2 + o3);
        float sq = o0*o0 + o1*o1 + o2*o2 + o3*o3;
        #pragma unroll
        for (int off = 1; off <= 16; off <<= 1){
            sm += __shfl_xor(sm, off, 64);
            sq += __shfl_xor(sq, off, 64);
        }
        const float mu  = sm * (1.f/128.f);
        float var = sq * (1.f/128.f) - mu*mu;
        var = var < 0.f ? 0.f : var;
        const float rstd = __builtin_amdgcn_rsqf(var + 1e-5f);
        outT[4*l2+0][nl] = (o0 - mu)*rstd*ga[0] + be[0];
        outT[4*l2+1][nl] = (o1 - mu)*rstd*ga[1] + be[1];
        outT[4*l2+2][nl] = (o2 - mu)*rstd*ga[2] + be[2];
        outT[4*l2+3][nl] = (o3 - mu)*rstd*ga[3] + be[3];
    }
    #undef NODE
    __syncthreads();

    float* ob = out + (size_t)b*CCH*NNODE + n0;
    #pragma unroll
    for (int it = 0; it < 16; ++it){
        const int c = it*8 + (t >> 5);
        const int coln = t & 31;
        ob[(size_t)c*NNODE + coln] = outT[c][coln];
    }
}

extern "C" void kernel_launch(void* const* d_in, const int* in_sizes, int n_in,
                              void* d_out, int out_size, void* d_ws, size_t ws_size,
                              hipStream_t stream)
{
    const float* x    = (const float*)d_in[0];
    const float* Wl   = (const float*)d_in[1];
    const float* attS = (const float*)d_in[2];
    const float* attD = (const float*)d_in[3];
    const float* bias = (const float*)d_in[4];
    const float* gamma= (const float*)d_in[5];
    const float* beta = (const float*)d_in[6];
    float* out = (float*)d_out;

    unsigned short* xpb = (unsigned short*)d_ws;                    // B*N*128 bf16
    float*          scb = (float*)(xpb + (size_t)BATCH*NNODE*CCH);  // B*N*16 f32
    unsigned*       Wb  = (unsigned*)(scb + (size_t)BATCH*NNODE*16);// 144*68 u32

    kW<<<dim3(16), 256, 0, stream>>>(Wl, attS, attD, Wb);
    kA<<<dim3(NNODE/128, BATCH), 256, 0, stream>>>(x, Wb, xpb, scb);
    kB<<<dim3(NNODE/32, BATCH), 256, 0, stream>>>(xpb, scb, bias, gamma, beta, out);
}

// Round 9
// 118.131 us; speedup vs baseline: 1.4203x; 1.0101x over previous
//
#include <hip/hip_runtime.h>
#include <stdint.h>

#define BATCH  4
#define CCH    128
#define GRID_H 128
#define GRID_W 128
#define NNODE  (GRID_H*GRID_W)   // 16384
#define NHEAD  8
#define DH     16
#define WPAD   68                // padded k2 row (64 + 4), keeps b128 align
#define WROWS  144               // 128 ch + 8 aS + 8 aD

typedef __attribute__((ext_vector_type(8))) short short8;
typedef __attribute__((ext_vector_type(4))) float f32x4;
typedef __attribute__((ext_vector_type(4))) unsigned u32x4;

__device__ inline unsigned short f2bf(float f){
    unsigned u = __float_as_uint(f);
    return (unsigned short)((u + 0x7FFFu + ((u >> 16) & 1u)) >> 16);
}
__device__ inline unsigned packbf(float a, float b){
    return (unsigned)f2bf(a) | ((unsigned)f2bf(b) << 16);
}
__device__ inline float bflo(unsigned u){ return __uint_as_float(u << 16); }
__device__ inline float bfhi(unsigned u){ return __uint_as_float(u & 0xFFFF0000u); }

// ---------------------------------------------------------------------------
// kW: pack augmented W' (144 cols: W | W@attS_h | W@attD_h) to bf16 k-pairs,
// co-major: Wb[co*WPAD + k2] = {bf16 W'[2k2][co], bf16 W'[2k2+1][co]}.
// ---------------------------------------------------------------------------
__global__ void kW(const float* __restrict__ Wl, const float* __restrict__ attS,
                   const float* __restrict__ attD, unsigned* __restrict__ Wb)
{
    __shared__ float Wa[8][16];
    const int t = threadIdx.x;
    const int cbase = blockIdx.x * 8;
    if (t < 128){
        int cl = t >> 4, j = t & 15;
        const float* av = (j < 8 ? attS + j*DH : attD + (j-8)*DH);
        const float* wr = Wl + (size_t)(cbase + cl)*CCH + (j & 7)*DH;
        float s = 0.f;
        #pragma unroll
        for (int d = 0; d < DH; ++d) s += wr[d]*av[d];
        Wa[cl][j] = s;
    }
    __syncthreads();
    for (int it = 0; it < 3; ++it){
        int flat = it*256 + t;
        if (flat < 576){
            int k2l = flat / 144, co = flat % 144;
            int k2 = blockIdx.x*4 + k2l;
            float w0, w1;
            if (co < CCH){
                w0 = Wl[(size_t)(2*k2)*CCH + co];
                w1 = Wl[(size_t)(2*k2+1)*CCH + co];
            } else {
                w0 = Wa[2*k2l][co-CCH];
                w1 = Wa[2*k2l+1][co-CCH];
            }
            Wb[co*WPAD + k2] = packbf(w0, w1);
        }
    }
}

// ---------------------------------------------------------------------------
// kA: D[m=co][n=node] = W'^T x (A=W', B=x). Coalesced b64 bf16 epilogue.
// XCD band swizzle: dispatch idx % 8 == XCD x owns grid rows [16x, 16x+16)
// so kB (same swizzle) reads xp/scb from the L2 that wrote it.
// ---------------------------------------------------------------------------
__global__ __launch_bounds__(256, 3) void kA(
    const float* __restrict__ x, const unsigned* __restrict__ Wbg,
    unsigned short* __restrict__ xpb, float* __restrict__ scb)
{
    __shared__ __align__(16) unsigned WbL[WROWS*WPAD];   // 39168 B

    const int t  = threadIdx.x;
    const int b  = blockIdx.y;
    const int i  = blockIdx.x;                       // 128 blocks (one row each)
    const int row = (i & 7)*16 + (i >> 3);           // XCD i%8 owns band
    const int n0 = row * 128;

    #pragma unroll
    for (int it = 0; it < 10; ++it){
        int f4 = it*256 + t;
        if (f4 < (WROWS*WPAD)/4)
            *(u32x4*)(&WbL[f4*4]) = *(const u32x4*)(Wbg + (size_t)f4*4);
    }
    __syncthreads();

    const int w = t >> 6, lane = t & 63;
    const int col = lane & 15, q = lane >> 4;
    const float* xb = x + (size_t)b*CCH*NNODE;
    const int nA = n0 + 2*w*16 + col;      // node-tile 0 node of this lane
    const int nB = nA + 16;                // node-tile 1

    f32x4 acc[2][9];
    #pragma unroll
    for (int mi = 0; mi < 2; ++mi)
        #pragma unroll
        for (int ct = 0; ct < 9; ++ct) acc[mi][ct] = (f32x4)(0.f);

    float xrA[8], xrB[8], x2A[8], x2B[8];
    #pragma unroll
    for (int j = 0; j < 8; ++j){
        const size_t co = (size_t)(q*8 + j)*NNODE;
        xrA[j] = xb[co + nA];
        xrB[j] = xb[co + nB];
    }

    union U { u32x4 u; short8 s; };
    #pragma unroll
    for (int kc = 0; kc < 4; ++kc){
        if (kc < 3){
            #pragma unroll
            for (int j = 0; j < 8; ++j){
                const size_t co = (size_t)((kc+1)*32 + q*8 + j)*NNODE;
                x2A[j] = xb[co + nA];
                x2B[j] = xb[co + nB];
            }
        }
        U fb0, fb1;
        #pragma unroll
        for (int i2 = 0; i2 < 4; ++i2){
            fb0.u[i2] = packbf(xrA[2*i2], xrA[2*i2+1]);
            fb1.u[i2] = packbf(xrB[2*i2], xrB[2*i2+1]);
        }
        const int kof = kc*16 + q*4;
        #pragma unroll
        for (int ct = 0; ct < 9; ++ct){
            U fa; fa.u = *(const u32x4*)(&WbL[(ct*16+col)*WPAD + kof]);
            acc[0][ct] = __builtin_amdgcn_mfma_f32_16x16x32_bf16(fa.s, fb0.s, acc[0][ct], 0, 0, 0);
            acc[1][ct] = __builtin_amdgcn_mfma_f32_16x16x32_bf16(fa.s, fb1.s, acc[1][ct], 0, 0, 0);
        }
        #pragma unroll
        for (int j = 0; j < 8; ++j){ xrA[j] = x2A[j]; xrB[j] = x2B[j]; }
    }

    // epilogue: lane holds co = ct*16 + q*4 + r for node (col). Standard layout.
    unsigned short* xr = xpb + (size_t)b*NNODE*CCH;
    float*          sr = scb + (size_t)b*NNODE*16;
    #pragma unroll
    for (int mi = 0; mi < 2; ++mi){
        const int n = mi ? nB : nA;
        #pragma unroll
        for (int ct = 0; ct < 8; ++ct){
            uint2 p;
            p.x = packbf(acc[mi][ct][0], acc[mi][ct][1]);
            p.y = packbf(acc[mi][ct][2], acc[mi][ct][3]);
            *(uint2*)(xr + (size_t)n*CCH + ct*16 + q*4) = p;
        }
        #pragma unroll
        for (int r = 0; r < 4; ++r)
            sr[(size_t)n*16 + q*4 + r] = acc[mi][8][r];   // 0..7 aS, 8..15 aD
    }
}

// ---------------------------------------------------------------------------
// kB: 32 nodes/block; half-wave per node, 4 channels/lane, 2-deep software
// pipeline, (256,4). XCD band swizzle matching kA: block j -> row
// (j%8)*16 + (j>>5), quarter (j>>3)&3 -> reads hit the local XCD L2.
// ---------------------------------------------------------------------------
__device__ inline void kb_issue(int n, const float* __restrict__ scB,
                                const uint2* __restrict__ xvb, int h, int l2,
                                int* vm, float* ad, float sc[9], uint2 xv[9])
{
    const int rr = n >> 7, cc = n & 127;
    const bool vU = rr > 0, vD = rr < GRID_H-1, vL = cc > 0, vR = cc < GRID_W-1;
    int m = 0;
    #pragma unroll
    for (int e = 0; e < 9; ++e){
        const int dr = e/3 - 1, dc = e%3 - 1;
        const bool vr_ = (dr < 0) ? vU : (dr > 0 ? vD : true);
        const bool vc_ = (dc < 0) ? vL : (dc > 0 ? vR : true);
        const bool v = vr_ && vc_;
        const int src = v ? (n + dr*GRID_W + dc) : n;
        m |= ((int)v) << e;
        sc[e] = scB[(size_t)src*16 + h];
        xv[e] = xvb[(size_t)src*32 + l2];
    }
    *ad = scB[(size_t)n*16 + 8 + h];
    *vm = m;
}

__global__ __launch_bounds__(256, 4) void kB(
    const unsigned short* __restrict__ xpb, const float* __restrict__ scb,
    const float* __restrict__ bias, const float* __restrict__ gamma,
    const float* __restrict__ beta, float* __restrict__ out)
{
    __shared__ float outT[CCH][33];
    const int t = threadIdx.x, w = t >> 6, lane = t & 63;
    const int h2 = lane >> 5, l2 = lane & 31;
    const int b  = blockIdx.y;
    const int j  = blockIdx.x;                        // 512 blocks
    const int row = (j & 7)*16 + (j >> 5);            // same band map as kA
    const int qtr = (j >> 3) & 3;
    const int n0 = row*128 + qtr*32;
    const uint2* xvb = (const uint2*)(xpb + (size_t)b*NNODE*CCH);
    const float* scB = scb + (size_t)b*NNODE*16;
    const int h = l2 >> 2;
    const f32x4 bi = *(const f32x4*)(bias  + 4*l2);
    const f32x4 ga = *(const f32x4*)(gamma + 4*l2);
    const f32x4 be = *(const f32x4*)(beta  + 4*l2);

    float scP[2][9]; uint2 xvP[2][9]; float adP[2]; int vmP[2];

    #define NODE(i) (n0 + w*8 + 2*(i) + h2)
    kb_issue(NODE(0), scB, xvb, h, l2, &vmP[0], &adP[0], scP[0], xvP[0]);

    #pragma unroll
    for (int i = 0; i < 4; ++i){
        const int cur = i & 1;
        if (i < 3)
            kb_issue(NODE(i+1), scB, xvb, h, l2, &vmP[cur^1], &adP[cur^1], scP[cur^1], xvP[cur^1]);

        const int vm = vmP[cur];
        const float* sc = scP[cur];
        const uint2* xv = xvP[cur];
        const float ad = adP[cur];
        const int nl = w*8 + 2*i + h2;

        float wt[9], den = 0.f;
        #pragma unroll
        for (int e = 0; e < 9; ++e){
            float sv = sc[e] + ad;
            sv = fmaxf(sv, 0.2f*sv);               // leaky relu
            sv = ((vm >> e) & 1) ? sv : -1e30f;    // exp(-1e30) -> 0
            float ex = __expf(sv);
            wt[e] = ex; den += ex;
        }
        den += wt[4];                              // appended self-loop
        const float inv = __builtin_amdgcn_rcpf(den);

        float a0 = 0.f, a1 = 0.f, a2 = 0.f, a3 = 0.f;
        #pragma unroll
        for (int e = 0; e < 9; ++e){
            float f = wt[e] * inv;
            if (e == 4) f += f;                    // self counted twice
            a0 += f * bflo(xv[e].x);
            a1 += f * bfhi(xv[e].x);
            a2 += f * bflo(xv[e].y);
            a3 += f * bfhi(xv[e].y);
        }

        float o0 = a0 + bi[0], o1 = a1 + bi[1], o2 = a2 + bi[2], o3 = a3 + bi[3];
        o0 = o0 > 0.f ? o0 : __expf(o0) - 1.f;
        o1 = o1 > 0.f ? o1 : __expf(o1) - 1.f;
        o2 = o2 > 0.f ? o2 : __expf(o2) - 1.f;
        o3 = o3 > 0.f ? o3 : __expf(o3) - 1.f;

        float sm = (o0 + o1) + (o2 + o3);
        float sq = o0*o0 + o1*o1 + o2*o2 + o3*o3;
        #pragma unroll
        for (int off = 1; off <= 16; off <<= 1){
            sm += __shfl_xor(sm, off, 64);
            sq += __shfl_xor(sq, off, 64);
        }
        const float mu  = sm * (1.f/128.f);
        float var = sq * (1.f/128.f) - mu*mu;
        var = var < 0.f ? 0.f : var;
        const float rstd = __builtin_amdgcn_rsqf(var + 1e-5f);
        outT[4*l2+0][nl] = (o0 - mu)*rstd*ga[0] + be[0];
        outT[4*l2+1][nl] = (o1 - mu)*rstd*ga[1] + be[1];
        outT[4*l2+2][nl] = (o2 - mu)*rstd*ga[2] + be[2];
        outT[4*l2+3][nl] = (o3 - mu)*rstd*ga[3] + be[3];
    }
    #undef NODE
    __syncthreads();

    float* ob = out + (size_t)b*CCH*NNODE + n0;
    #pragma unroll
    for (int it = 0; it < 16; ++it){
        const int c = it*8 + (t >> 5);
        const int coln = t & 31;
        ob[(size_t)c*NNODE + coln] = outT[c][coln];
    }
}

extern "C" void kernel_launch(void* const* d_in, const int* in_sizes, int n_in,
                              void* d_out, int out_size, void* d_ws, size_t ws_size,
                              hipStream_t stream)
{
    const float* x    = (const float*)d_in[0];
    const float* Wl   = (const float*)d_in[1];
    const float* attS = (const float*)d_in[2];
    const float* attD = (const float*)d_in[3];
    const float* bias = (const float*)d_in[4];
    const float* gamma= (const float*)d_in[5];
    const float* beta = (const float*)d_in[6];
    float* out = (float*)d_out;

    unsigned short* xpb = (unsigned short*)d_ws;                    // B*N*128 bf16
    float*          scb = (float*)(xpb + (size_t)BATCH*NNODE*CCH);  // B*N*16 f32
    unsigned*       Wb  = (unsigned*)(scb + (size_t)BATCH*NNODE*16);// 144*68 u32

    kW<<<dim3(16), 256, 0, stream>>>(Wl, attS, attD, Wb);
    kA<<<dim3(NNODE/128, BATCH), 256, 0, stream>>>(x, Wb, xpb, scb);
    kB<<<dim3(NNODE/32, BATCH), 256, 0, stream>>>(xpb, scb, bias, gamma, beta, out);
}